// Round 1
// 503.294 us; speedup vs baseline: 1.1678x; 1.1678x over previous
//
#include <hip/hip_runtime.h>
#include <hip/hip_bf16.h>

#define CIN   512
#define COUT  512
#define HW    4096
#define PADW  66
#define NB    16
#define KTOT  4608            // 9 taps * 512
#define BUFSZ 65536           // one double-buffer half: A 32K + B 32K
#define BOFF  32768           // B region offset within a buffer

static constexpr float LIN_SCALE = 0.044194173824159216f;  // 1/sqrt(512)
static constexpr float W_SCALE   = 0.014731391274719738f;  // 1/sqrt(512*9)

typedef __attribute__((ext_vector_type(8))) short bf16x8;
typedef __attribute__((ext_vector_type(4))) float f32x4;

__device__ __forceinline__ unsigned short f2us(float f) {
    __hip_bfloat16 h = __float2bfloat16(f); unsigned short u; __builtin_memcpy(&u, &h, 2); return u;
}

typedef const __attribute__((address_space(1))) unsigned int guint;
typedef __attribute__((address_space(3))) unsigned int luint;
__device__ __forceinline__ void gload_lds16(const void* g, void* l) {
    __builtin_amdgcn_global_load_lds((guint*)g, (luint*)l, 16, 0, 0);
}

// ---------------- s[n][i] = lin_scale * style[n] . style_w[i] + style_b[i] ----------------
__global__ void k_style(const float* __restrict__ style,
                        const float* __restrict__ style_w,
                        const float* __restrict__ style_b,
                        float* __restrict__ s) {
    int wid  = (blockIdx.x * blockDim.x + threadIdx.x) >> 6;
    int lane = threadIdx.x & 63;
    int n = wid >> 9, i = wid & 511;
    float sum = 0.f;
    for (int j = lane; j < 512; j += 64)
        sum += style[n * 512 + j] * style_w[i * 512 + j];
    for (int m = 32; m; m >>= 1) sum += __shfl_xor(sum, m, 64);
    if (lane == 0) s[n * 512 + i] = sum * LIN_SCALE + style_b[i];
}

// ---- wsq[o][i] = sum_tap (w*wscale)^2 ; wt[o][tap][i] = bf16(w*wscale)  (o-major, K flat)
__global__ void k_wprep(const float* __restrict__ weight,
                        float* __restrict__ wsq,
                        __hip_bfloat16* __restrict__ wt) {
    int oi = blockIdx.x * 256 + threadIdx.x;   // 0..262143  (= o*512 + i)
    int o = oi >> 9, i = oi & 511;
    float sq = 0.f;
#pragma unroll
    for (int tp = 0; tp < 9; ++tp) {
        float v = weight[(size_t)oi * 9 + tp] * W_SCALE;
        sq += v * v;
        wt[(size_t)o * KTOT + tp * 512 + i] = __float2bfloat16(v);
    }
    wsq[oi] = sq;
}

// ---------------- demod[n][o] = rsqrt(sum_i wsq[o][i]*s[n][i]^2 + eps) --------------------
__global__ void k_demod(const float* __restrict__ wsq, const float* __restrict__ s,
                        float* __restrict__ demod) {
    int wid  = (blockIdx.x * blockDim.x + threadIdx.x) >> 6;
    int lane = threadIdx.x & 63;
    int n = wid >> 9, o = wid & 511;
    float sum = 0.f;
    for (int i = lane; i < 512; i += 64) {
        float sv = s[n * 512 + i];
        sum += wsq[o * 512 + i] * sv * sv;
    }
    for (int m = 32; m; m >>= 1) sum += __shfl_xor(sum, m, 64);
    if (lane == 0) demod[n * 512 + o] = rsqrtf(sum + 1e-8f);
}

// ---------------- zero the pad border of xs_t [16][66][66][512] ---------------------------
__global__ void k_border(__hip_bfloat16* __restrict__ xs) {
    int bp = blockIdx.x, n = blockIdx.y, t = threadIdx.x;  // 260 border pixels, 64 threads
    int hp, wp;
    if (bp < 66)       { hp = 0;  wp = bp; }
    else if (bp < 132) { hp = 65; wp = bp - 66; }
    else { int k2 = bp - 132; hp = 1 + (k2 >> 1); wp = (k2 & 1) ? 65 : 0; }
    uint4 z = make_uint4(0u, 0u, 0u, 0u);
    *(uint4*)(xs + (((size_t)n * PADW * PADW) + hp * PADW + wp) * 512 + t * 8) = z;
}

// ---- xs_t[n][h+1][w+1][i] = bf16(x[n][i][h][w] * s[n][i])  (f32 NCHW -> padded bf16 NHWC)
__global__ void k_xs(const float* __restrict__ x, const float* __restrict__ s,
                     __hip_bfloat16* __restrict__ xs) {
    const int h = blockIdx.x;   // 0..63
    const int n = blockIdx.y;   // 0..15
    const int t = threadIdx.x;  // 0..255
    const int PITCH = 66;
    __shared__ float lds[64 * 66];
    for (int ic = 0; ic < 8; ++ic) {
        const int i0 = ic * 64;
        __syncthreads();
#pragma unroll
        for (int j = 0; j < 4; ++j) {
            int idx = j * 256 + t;
            int il = idx >> 4;
            int wq = (idx & 15) * 4;
            float4 v = *(const float4*)(x + (((size_t)n * 512 + i0 + il) * HW) + h * 64 + wq);
            float* dst = &lds[il * PITCH + wq];
            dst[0] = v.x; dst[1] = v.y; dst[2] = v.z; dst[3] = v.w;
        }
        __syncthreads();
#pragma unroll
        for (int j = 0; j < 2; ++j) {
            int idx = j * 256 + t;
            int wp = idx >> 3;
            int ib = (idx & 7) * 8;
            unsigned short tmp[8];
#pragma unroll
            for (int r = 0; r < 8; ++r) {
                float xv = lds[(ib + r) * PITCH + wp];
                float sv = s[n * 512 + i0 + ib + r];
                tmp[r] = f2us(xv * sv);
            }
            uint4 o;
            o.x = (unsigned)tmp[0] | ((unsigned)tmp[1] << 16);
            o.y = (unsigned)tmp[2] | ((unsigned)tmp[3] << 16);
            o.z = (unsigned)tmp[4] | ((unsigned)tmp[5] << 16);
            o.w = (unsigned)tmp[6] | ((unsigned)tmp[7] << 16);
            *(uint4*)(xs + ((size_t)((n * PADW + h + 1) * PADW + (wp + 1))) * 512 + i0 + ib) = o;
        }
    }
}

// ---------------- main conv: 256x256 tile, 8 waves, 4-phase/K-step counted-vmcnt ----------
// A = wt[o][k] (k = tap*512+i, flat K=4608), B = xs[n][h+kh][w+kw][i] implicit.
// LDS: 2 x (A 256x64 bf16 | B 256x64 bf16) = 128 KiB, XOR-swizzled 16B chunks
// (phys_chunk = logical_chunk ^ (row&7)) via pre-swizzled global source (linear LDS dest).
#define BAR      __builtin_amdgcn_s_barrier()
#define WAITLGKM asm volatile("s_waitcnt lgkmcnt(0)" ::: "memory")
#define LOAD_B(CH) { _Pragma("unroll") for (int t_ = 0; t_ < 4; ++t_) \
    bfr[t_] = *(const bf16x8*)(cb + BOFF + bRow + t_ * 2048 + (CH)); }
#define LOAD_A(MG, CH) { _Pragma("unroll") for (int t_ = 0; t_ < 4; ++t_) \
    af[t_] = *(const bf16x8*)(cb + aRow + ((MG) * 4 + t_) * 2048 + (CH)); }
#define DO_MFMA(MG) { __builtin_amdgcn_s_setprio(1); \
    _Pragma("unroll") for (int m_ = 0; m_ < 4; ++m_) \
    _Pragma("unroll") for (int n_ = 0; n_ < 4; ++n_) \
        acc[(MG) * 4 + m_][n_] = __builtin_amdgcn_mfma_f32_16x16x32_bf16( \
            af[m_], bfr[n_], acc[(MG) * 4 + m_][n_], 0, 0, 0); \
    __builtin_amdgcn_s_setprio(0); }

__global__ __launch_bounds__(512, 2) void k_conv(
        const __hip_bfloat16* __restrict__ wt,     // [512][4608]  (o-major, K flat)
        const __hip_bfloat16* __restrict__ xs,     // [16][66][66][512]
        const float* __restrict__ demod,           // [16][512]
        float* __restrict__ out) {                 // [16][512][64][64] f32
    __shared__ __attribute__((aligned(16))) char smem[2 * BUFSZ];
    const int tid  = threadIdx.x;
    const int wv   = tid >> 6, lane = tid & 63;
    const int wm   = wv >> 2,  wn   = wv & 3;      // 2M x 4N wave grid

    // XCD-aware block decode: 512 blocks, bid%8 = XCD -> each XCD owns 2 samples
    const int bid = blockIdx.x;
    const int xcd = bid & 7, idx = bid >> 3;       // idx 0..63
    const int pT  = idx & 15;                      // pixel tile (256 px = 4 rows)
    const int o0  = ((idx >> 4) & 1) * 256;        // output-channel tile
    const int smp = xcd * 2 + (idx >> 5);          // sample

    const __hip_bfloat16* xsn = xs + (size_t)smp * (PADW * PADW * 512);

    // ---- staging lane geometry (pre-swizzled source, linear LDS dest) ----
    const int rw = lane >> 3, cl = lane & 7;
    const int lc = cl ^ rw;                        // swizzle involution
    const size_t aOff = (size_t)(wv * 8 + rw) * KTOT + lc * 8;   // elements
    const size_t bOff = (size_t)(wv * 8 + rw) * 512  + lc * 8;
    const __hip_bfloat16* aStage = wt  + (size_t)o0 * KTOT + aOff;
    const __hip_bfloat16* bStage = xsn + bOff;

    // ---- fragment read geometry ----
    const int col = lane & 15, qd = lane >> 4;
    const int ch0 = ((qd)     ^ (col & 7)) << 4;   // kk=0 chunk byte offset (swizzled)
    const int ch1 = ((qd + 4) ^ (col & 7)) << 4;   // kk=1
    const int aRow = (wm * 128 + col) * 128;       // byte offset of A row
    const int bRow = (wn * 64  + col) * 128;

    f32x4 acc[8][4] = {};

    // ---- prologue: stage K-step 0 into buf0; order [B0..B3, A0, A2, A1, A3] ----
    {
        char* nbB = smem + BOFF + wv * 1024;
        char* nbA = smem + wv * 1024;
        const __hip_bfloat16* bS = bStage + (size_t)(pT * 4) * 33792;  // tap0, c0
        gload_lds16(bS,              nbB);
        gload_lds16(bS + 33792,      nbB + 8192);
        gload_lds16(bS + 2 * 33792,  nbB + 2 * 8192);
        gload_lds16(bS + 3 * 33792,  nbB + 3 * 8192);
        gload_lds16(aStage,              nbA);
        gload_lds16(aStage + 2 * 294912, nbA + 2 * 8192);
        gload_lds16(aStage + 294912,     nbA + 8192);
        gload_lds16(aStage + 3 * 294912, nbA + 3 * 8192);
        asm volatile("s_waitcnt vmcnt(2)" ::: "memory");   // first 6 landed
        BAR;
    }

    // ---- main loop: 72 K-steps (9 taps x 8 chunks); last iter (71) peeled as tail ----
    for (int kt = 0; kt < 71; ++kt) {
        char* cb = smem + (kt & 1) * BUFSZ;
        char* nb = smem + ((kt + 1) & 1) * BUFSZ;
        const int kt1  = kt + 1;
        const int tap1 = kt1 >> 3, c1 = kt1 & 7;
        const int kh1  = tap1 / 3, kw1 = tap1 - kh1 * 3;
        const __hip_bfloat16* aS = aStage + (size_t)kt1 * 64;
        const __hip_bfloat16* bS = bStage +
            (size_t)((pT * 4 + kh1) * PADW + kw1) * 512 + c1 * 64;
        char* nbB = nb + BOFF + wv * 1024;
        char* nbA = nb + wv * 1024;

        bf16x8 af[4], bfr[4];

        // phase 0: kk=0, m 0..3   | stage B0,B1,B2 (next step)
        LOAD_B(ch0); LOAD_A(0, ch0);
        gload_lds16(bS,             nbB);
        gload_lds16(bS + 33792,     nbB + 8192);
        gload_lds16(bS + 2 * 33792, nbB + 2 * 8192);
        BAR; WAITLGKM;
        DO_MFMA(0);
        asm volatile("s_waitcnt vmcnt(3)" ::: "memory");   // retire prev A1,A3
        BAR;

        // phase 1: kk=0, m 4..7   | stage B3,A0,A2
        LOAD_A(1, ch0);
        gload_lds16(bS + 3 * 33792, nbB + 3 * 8192);
        gload_lds16(aS,             nbA);
        gload_lds16(aS + 2 * 294912, nbA + 2 * 8192);
        BAR; WAITLGKM;
        DO_MFMA(1);
        BAR;

        // phase 2: kk=1, m 0..3   | stage A1,A3
        LOAD_B(ch1); LOAD_A(0, ch1);
        gload_lds16(aS + 294912,     nbA + 8192);
        gload_lds16(aS + 3 * 294912, nbA + 3 * 8192);
        BAR; WAITLGKM;
        DO_MFMA(0);
        BAR;

        // phase 3: kk=1, m 4..7
        LOAD_A(1, ch1);
        BAR; WAITLGKM;
        DO_MFMA(1);
        asm volatile("s_waitcnt vmcnt(2)" ::: "memory");   // retire 6 needed next phase 0
        BAR;
    }

    // ---- tail: K-step 71, no staging; single drain ----
    {
        char* cb = smem + BUFSZ;                   // 71 & 1 = 1
        asm volatile("s_waitcnt vmcnt(0)" ::: "memory");
        BAR;
        bf16x8 af[4], bfr[4];
        LOAD_B(ch0); LOAD_A(0, ch0); DO_MFMA(0);
        LOAD_A(1, ch0);              DO_MFMA(1);
        LOAD_B(ch1); LOAD_A(0, ch1); DO_MFMA(0);
        LOAD_A(1, ch1);              DO_MFMA(1);
    }

    // ---- epilogue: scale by demod, store f32 NCHW ----
    const int hwBase = pT * 256 + wn * 64 + col;
#pragma unroll
    for (int m = 0; m < 8; ++m) {
#pragma unroll
        for (int rg = 0; rg < 4; ++rg) {
            const int o = o0 + wm * 128 + m * 16 + qd * 4 + rg;
            const float dm = demod[smp * 512 + o];
            float* orow = out + ((size_t)(smp * COUT + o)) * HW + hwBase;
#pragma unroll
            for (int nn = 0; nn < 4; ++nn)
                orow[nn * 16] = acc[m][nn][rg] * dm;
        }
    }
}

extern "C" void kernel_launch(void* const* d_in, const int* in_sizes, int n_in,
                              void* d_out, int out_size, void* d_ws, size_t ws_size,
                              hipStream_t stream) {
    const float* x       = (const float*)d_in[0];
    const float* style   = (const float*)d_in[1];
    const float* weight  = (const float*)d_in[2];
    const float* style_w = (const float*)d_in[3];
    const float* style_b = (const float*)d_in[4];
    float* out = (float*)d_out;

    char* ws = (char*)d_ws;
    // ws layout (bytes): s 0..32K | wsq 32K..1.03M | demod .. | wt 512*4608*2 | xs_t 71.3M
    float*          s_buf  = (float*)(ws + 0);
    float*          wsq    = (float*)(ws + 32768);
    float*          demod  = (float*)(ws + 1081344);
    __hip_bfloat16* wt     = (__hip_bfloat16*)(ws + 1114112);
    __hip_bfloat16* xs     = (__hip_bfloat16*)(ws + 5832704);
    // total = 77,201,408 bytes

    k_style <<<dim3(2048),     dim3(256), 0, stream>>>(style, style_w, style_b, s_buf);
    k_wprep <<<dim3(1024),     dim3(256), 0, stream>>>(weight, wsq, wt);
    k_demod <<<dim3(2048),     dim3(256), 0, stream>>>(wsq, s_buf, demod);
    k_border<<<dim3(260, 16),  dim3(64),  0, stream>>>(xs);
    k_xs    <<<dim3(64, 16),   dim3(256), 0, stream>>>(x, s_buf, xs);
    k_conv  <<<dim3(512),      dim3(512), 0, stream>>>(wt, xs, demod, out);
}